// Round 12
// baseline (957.317 us; speedup 1.0000x reference)
//
#include <hip/hip_runtime.h>

constexpr int L      = 128;
constexpr int TDIM   = 1024;
constexpr int NBATCH = 128;
constexpr int START  = L - 2; // 126
constexpr int STOP   = L - 1; // 127
constexpr int BSUB   = 16;    // batches per chain
constexpr int NBLK   = NBATCH / BSUB; // 8 chains total

typedef short bf16x8 __attribute__((ext_vector_type(8)));
typedef float f32x4  __attribute__((ext_vector_type(4)));
typedef int   i32x4  __attribute__((ext_vector_type(4)));

union B4 { i32x4 i; bf16x8 v; };

__device__ __forceinline__ short f2bf(float f) {
    unsigned x = __float_as_uint(f);
    return (short)((x + 0x7fffu + ((x >> 16) & 1u)) >> 16); // RNE
}
__device__ __forceinline__ unsigned pkbf(float lo, float hi) {
    unsigned r;
    asm("v_cvt_pk_bf16_f32 %0, %1, %2" : "=v"(r) : "v"(lo), "v"(hi));
    return r;
}

// ---------------------------------------------------------------------------
// Precompute: pexp = masked bf16 exp(pred) (layout verified exact R4-R9).
// ---------------------------------------------------------------------------
__global__ __launch_bounds__(256)
void crf_pexp(const float* __restrict__ pred, const int* __restrict__ seq_len,
              unsigned short* __restrict__ pexp)
{
    int gid  = blockIdx.x * 256 + threadIdx.x;  // 2,097,152 total
    int lane = gid & 63;
    int c    = (gid >> 6) & 3;
    int row  = (gid >> 8) & 1023;
    int blk  = gid >> 18;
    int l15 = lane & 15, l4 = lane >> 4;
    int b = blk * 16 + l15;
    bool live = row < seq_len[b];

    const float* src = pred + ((size_t)b * TDIM + row) * L + 32 * c + 4 * l4;
    f32x4 v0 = *(const f32x4*)(src);
    f32x4 v1 = *(const f32x4*)(src + 16);

    float e0[4], e1[4];
#pragma unroll
    for (int r = 0; r < 4; ++r) {
        int s0 = 32 * c + 4 * l4 + r;
        int s1 = s0 + 16;
        e0[r] = (live && s0 < 126) ? __expf(v0[r]) : 0.0f;
        e1[r] = (live && s1 < 126) ? __expf(v1[r]) : 0.0f;
    }
    i32x4 out;
    out[0] = (int)pkbf(e0[0], e0[1]);
    out[1] = (int)pkbf(e0[2], e0[3]);
    out[2] = (int)pkbf(e1[0], e1[1]);
    out[3] = (int)pkbf(e1[2], e1[3]);
    *(i32x4*)((char*)pexp + (size_t)gid * 16) = out;
}

// ---------------------------------------------------------------------------
// Chain kernel. MODE 1: TWO chains per wave, 4 blocks x 1 wave.
//   Phase 1 of step t: stages of chain A (unpack D_A(t) -> B_A=u_A(t))
//                      interleaved with MFMA groups of chain B (B_B -> D_B).
//   Phase 2: mirrored. MFMA pipe stays fed during the other chain's VALU.
// All numerics/macros = verified tier-1 text, parameterized per chain.
// MODE 0: fallback single chain per block on raw pred (verified).
// ---------------------------------------------------------------------------
struct PB { i32x4 c[4]; };
struct PF { f32x4 q[8]; };

// MFMA group KT from B-array BS into ACCO (T order 0,4,1,5,2,6,3,7)
#define GRP(ACCO, KT, BS, SEED)                                              \
  {                                                                          \
    ACCO[0] = __builtin_amdgcn_mfma_f32_16x16x32_bf16(A[0][KT], BS[KT].v, (SEED) ? Z4 : ACCO[0], 0, 0, 0); \
    ACCO[4] = __builtin_amdgcn_mfma_f32_16x16x32_bf16(A[4][KT], BS[KT].v, (SEED) ? Z4 : ACCO[4], 0, 0, 0); \
    ACCO[1] = __builtin_amdgcn_mfma_f32_16x16x32_bf16(A[1][KT], BS[KT].v, (SEED) ? Z4 : ACCO[1], 0, 0, 0); \
    ACCO[5] = __builtin_amdgcn_mfma_f32_16x16x32_bf16(A[5][KT], BS[KT].v, (SEED) ? Z4 : ACCO[5], 0, 0, 0); \
    ACCO[2] = __builtin_amdgcn_mfma_f32_16x16x32_bf16(A[2][KT], BS[KT].v, (SEED) ? Z4 : ACCO[2], 0, 0, 0); \
    ACCO[6] = __builtin_amdgcn_mfma_f32_16x16x32_bf16(A[6][KT], BS[KT].v, (SEED) ? Z4 : ACCO[6], 0, 0, 0); \
    ACCO[3] = __builtin_amdgcn_mfma_f32_16x16x32_bf16(A[3][KT], BS[KT].v, (SEED) ? Z4 : ACCO[3], 0, 0, 0); \
    ACCO[7] = __builtin_amdgcn_mfma_f32_16x16x32_bf16(A[7][KT], BS[KT].v, (SEED) ? Z4 : ACCO[7], 0, 0, 0); \
    __builtin_amdgcn_sched_group_barrier(0x008, 8, 0);                       \
  }

// Stage pair (TA,TB) of one chain: verified tier-1 word-extract text.
#define STG(TA, TB, AIN, PBUF, BT, CHK, SCL, APS, MLOC)                      \
  {                                                                          \
    unsigned wa0 = (unsigned)PBUF.c[(TA) >> 1][((TA) & 1) * 2 + 0];          \
    unsigned wa1 = (unsigned)PBUF.c[(TA) >> 1][((TA) & 1) * 2 + 1];          \
    unsigned wb0 = (unsigned)PBUF.c[(TB) >> 1][((TB) & 1) * 2 + 0];          \
    unsigned wb1 = (unsigned)PBUF.c[(TB) >> 1][((TB) & 1) * 2 + 1];          \
    float ua0 = AIN[TA][0] * __uint_as_float(wa0 << 16);                     \
    float ua1 = AIN[TA][1] * __uint_as_float(wa0 & 0xffff0000u);             \
    float ua2 = AIN[TA][2] * __uint_as_float(wa1 << 16);                     \
    float ua3 = AIN[TA][3] * __uint_as_float(wa1 & 0xffff0000u);             \
    float ub0 = AIN[TB][0] * __uint_as_float(wb0 << 16);                     \
    float ub1 = AIN[TB][1] * __uint_as_float(wb0 & 0xffff0000u);             \
    float ub2 = AIN[TB][2] * __uint_as_float(wb1 << 16);                     \
    float ub3 = AIN[TB][3] * __uint_as_float(wb1 & 0xffff0000u);             \
    if ((SCL) && APS) {                                                      \
      ua0 *= 0x1p-64f; ua1 *= 0x1p-64f; ua2 *= 0x1p-64f; ua3 *= 0x1p-64f;    \
      ub0 *= 0x1p-64f; ub1 *= 0x1p-64f; ub2 *= 0x1p-64f; ub3 *= 0x1p-64f;    \
    }                                                                        \
    if (CHK) {                                                               \
      MLOC = fmaxf(MLOC, fmaxf(fmaxf(fmaxf(ua0, ua1), fmaxf(ua2, ua3)),      \
                               fmaxf(fmaxf(ub0, ub1), fmaxf(ub2, ub3))));    \
    }                                                                        \
    BT[TA].i[0] = (int)pkbf(ua0, ua1);                                       \
    BT[TA].i[1] = (int)pkbf(ua2, ua3);                                       \
    BT[TA].i[2] = (int)pkbf(ub0, ub1);                                       \
    BT[TA].i[3] = (int)pkbf(ub2, ub3);                                       \
    __builtin_amdgcn_sched_group_barrier(0x002, 20, 0);                      \
  }

// One phase at step tS: stages of OWN chain + groups of OTHER chain.
// AIN/PBUF/BT/APS/CV/RES/RESC/SROW/PXB = own chain; AOUT/BS = other chain.
#define PHASE(T_, AIN, AOUT, PBUF, BT, BS, CHK, SCL, APS, CV, RES, RESC, SROW, PXB) \
  {                                                                          \
    const int tS = (T_);                                                     \
    float mloc = 0.0f; (void)mloc;                                           \
    STG(0, 4, AIN, PBUF, BT, CHK, SCL, APS, mloc)                            \
    GRP(AOUT, 0, BS, true)                                                   \
    STG(1, 5, AIN, PBUF, BT, CHK, SCL, APS, mloc)                            \
    GRP(AOUT, 1, BS, false)                                                  \
    STG(2, 6, AIN, PBUF, BT, CHK, SCL, APS, mloc)                            \
    GRP(AOUT, 2, BS, false)                                                  \
    STG(3, 7, AIN, PBUF, BT, CHK, SCL, APS, mloc)                            \
    { bool hit = (tS == (SROW));                                             \
      RES  = hit ? AIN[7][3] : RES;                                          \
      RESC = hit ? CV : RESC; }                                              \
    if ((SCL) && APS) { CV += 44.3614195558365f; APS = false; }              \
    GRP(AOUT, 3, BS, false)                                                  \
    if (CHK) APS = (__ballot(mloc > 0x1p80f) != 0ull);                       \
    loadPB(PBUF, min(tS, TDIM - 1), PXB);                                    \
  }

template<int MODE>   // 1 = two-chain interleaved (pexp), 0 = raw-pred fallback
__global__ __launch_bounds__(64, 1)
void crf_chain(const float* __restrict__ pred,
               const float* __restrict__ trans,
               const int* __restrict__ seq_len,
               const void* __restrict__ px,
               float* __restrict__ fwd_out)
{
    const int lane = threadIdx.x;
    const int l15 = lane & 15, l4 = lane >> 4;
    const int blk = blockIdx.x;

    // A-frags (shared by both chains): A[T][kt] elem e = exp(trans[s][16T+l15]),
    // s = 16*kt + 64*(e>>2) + 4*l4 + (e&3)   (verified exact)
    bf16x8 A[8][4];
#pragma unroll
    for (int T = 0; T < 8; ++T)
#pragma unroll
        for (int kt = 0; kt < 4; ++kt) {
            bf16x8 v;
#pragma unroll
            for (int e = 0; e < 8; ++e) {
                int s = 16 * kt + 64 * (e >> 2) + 4 * l4 + (e & 3);
                v[e] = f2bf(__expf(trans[s * L + 16 * T + l15]));
            }
            A[T][kt] = v;
        }

    const f32x4 Z4 = {0.f, 0.f, 0.f, 0.f};

    auto loadPB = [&](PB& p, int row, const char* pxb) {
        const i32x4* s = (const i32x4*)(pxb + (size_t)row * 4096) + lane;
        p.c[0] = s[0]; p.c[1] = s[64]; p.c[2] = s[128]; p.c[3] = s[192];
    };

    if constexpr (MODE == 1) {
        const int bA = blk * 32 + l15;        // chain A batch
        const int bB = blk * 32 + 16 + l15;   // chain B batch
        const char* pxbA = (const char*)px + ((size_t)(2 * blk) << 22);
        const char* pxbB = (const char*)px + ((size_t)(2 * blk + 1) << 22);

        const int srow1A = seq_len[bA] + 1;
        const int srow1B = seq_len[bB] + 1;

        int mx = max(srow1A, srow1B);
#pragma unroll
        for (int d = 1; d < 16; d <<= 1) mx = max(mx, __shfl_xor(mx, d));
        const int tmaxR = __builtin_amdgcn_readfirstlane((mx + 1) & ~1); // even

        B4 B_A[4], B_B[4];
#pragma unroll
        for (int kt = 0; kt < 4; ++kt) {
            B_A[kt].i = (i32x4){0, 0, 0, 0};
            B_B[kt].i = (i32x4){0, 0, 0, 0};
        }
        if (l4 == 3) { B_A[3].i[3] = 0x3F80; B_B[3].i[3] = 0x3F80; } // START=1

        float CA = 0.0f, CB = 0.0f;
        bool  apsA = false, apsB = false;
        float resA = 1.0f, resCA = 0.0f, resB = 1.0f, resCB = 0.0f;

        PB pA, pB;
        loadPB(pA, 0, pxbA);
        loadPB(pB, 0, pxbB);

        f32x4 accA[8], accB[8];
        // Prologue: accA = D_A(1) from B_A (u0). accB produced in first phase.
        GRP(accA, 0, B_A, true)
        GRP(accA, 1, B_A, false)
        GRP(accA, 2, B_A, false)
        GRP(accA, 3, B_A, false)

        for (int t0 = 1; t0 < tmaxR; t0 += 2) {
            // superstep t0 (check parity)
            PHASE(t0, accA, accB, pA, B_A, B_B, true, false, apsA, CA, resA, resCA, srow1A, pxbA)
            PHASE(t0, accB, accA, pB, B_B, B_A, true, false, apsB, CB, resB, resCB, srow1B, pxbB)
            // superstep t0+1 (apply parity)
            PHASE(t0 + 1, accA, accB, pA, B_A, B_B, false, true, apsA, CA, resA, resCA, srow1A, pxbA)
            PHASE(t0 + 1, accB, accA, pB, B_B, B_A, false, true, apsB, CB, resB, resCB, srow1B, pxbB)
        }

        if (l4 == 3) {
            fwd_out[bA] = __logf(resA) + resCA;
            fwd_out[bB] = __logf(resB) + resCB;
        }
    } else {
        // Fallback: single chain per block on raw pred (verified text).
        const int b = blk * BSUB + l15;
        const int srow1 = seq_len[b] + 1;

        int mx = srow1;
#pragma unroll
        for (int d = 1; d < 16; d <<= 1) mx = max(mx, __shfl_xor(mx, d));
        const int tmaxR = __builtin_amdgcn_readfirstlane((mx + 1) & ~1);

        B4 B[4];
#pragma unroll
        for (int kt = 0; kt < 4; ++kt) B[kt].i = (i32x4){0, 0, 0, 0};
        if (l4 == 3) B[3].i[3] = 0x3F80;

        float C = 0.0f;
        bool  applyScale = false;
        float res = 1.0f, resC = 0.0f;

        const float* pfb = pred + (size_t)b * TDIM * L + 4 * l4;
        PF fa, fb;
        auto loadPF = [&](PF& p, int row) {
            const f32x4* s = (const f32x4*)(pfb + (size_t)row * L);
#pragma unroll
            for (int T = 0; T < 8; ++T) p.q[T] = s[T * 4];
        };
        loadPF(fa, 0); loadPF(fb, 1);
        f32x4 acc[8];
        auto stepF = [&](int t, PF& pf, bool chk) {
#pragma unroll
            for (int T = 0; T < 8; ++T)
                acc[T] = __builtin_amdgcn_mfma_f32_16x16x32_bf16(A[T][0], B[0].v, Z4, 0, 0, 0);
#pragma unroll
            for (int kt = 1; kt < 4; ++kt)
#pragma unroll
                for (int T = 0; T < 8; ++T)
                    acc[T] = __builtin_amdgcn_mfma_f32_16x16x32_bf16(A[T][kt], B[kt].v, acc[T], 0, 0, 0);

            bool hit = (t == srow1);
            res  = hit ? acc[7][3] : res;
            resC = hit ? C : resC;

            const bool live = (t < srow1);
            float u[8][4];
#pragma unroll
            for (int T = 0; T < 8; ++T)
#pragma unroll
                for (int r = 0; r < 4; ++r) {
                    bool dead = !live || (T == 7 && l4 == 3 && r >= 2);
                    u[T][r] = dead ? 0.0f : acc[T][r] * __expf(pf.q[T][r]);
                }
            if (applyScale) {
#pragma unroll
                for (int T = 0; T < 8; ++T)
#pragma unroll
                    for (int r = 0; r < 4; ++r) u[T][r] *= 0x1p-64f;
                C += 44.3614195558365f;
            }
            applyScale = false;
            if (chk) {
                float m[8];
#pragma unroll
                for (int T = 0; T < 8; ++T)
                    m[T] = fmaxf(fmaxf(u[T][0], u[T][1]), fmaxf(u[T][2], u[T][3]));
                float mx4 = fmaxf(fmaxf(fmaxf(m[0], m[1]), fmaxf(m[2], m[3])),
                                  fmaxf(fmaxf(m[4], m[5]), fmaxf(m[6], m[7])));
                applyScale = (__ballot(mx4 > 0x1p80f) != 0ull);
            }
#pragma unroll
            for (int kt = 0; kt < 4; ++kt) {
                B[kt].i[0] = (int)pkbf(u[kt][0], u[kt][1]);
                B[kt].i[1] = (int)pkbf(u[kt][2], u[kt][3]);
                B[kt].i[2] = (int)pkbf(u[kt + 4][0], u[kt + 4][1]);
                B[kt].i[3] = (int)pkbf(u[kt + 4][2], u[kt + 4][3]);
            }
            loadPF(pf, min(t + 1, TDIM - 1));
        };
        for (int t0 = 0; t0 < tmaxR; t0 += 2) {
            stepF(t0 + 1, fa, true);
            stepF(t0 + 2, fb, false);
        }
        if (l4 == 3)
            fwd_out[b] = __logf(res) + resC;
    }
}

// ---------------------------------------------------------------------------
// Gold path score (unchanged, verified exact).
// ---------------------------------------------------------------------------
__global__ __launch_bounds__(256)
void crf_score(const float* __restrict__ pred,
               const float* __restrict__ trans,
               const int* __restrict__ tags,
               const int* __restrict__ seq_len,
               float* __restrict__ score_out)
{
    const int b = blockIdx.x;
    const int tid = threadIdx.x;
    const int sl = seq_len[b];
    const int* tg = tags + b * TDIM;

    float s = 0.0f;
    for (int t = tid; t < sl; t += 256) {
        int tag = tg[t];
        s += pred[((long)b * TDIM + t) * L + tag];
        int prev = (t == 0) ? START : tg[t - 1];
        s += trans[prev * L + tag];
    }
    if (tid == 0) s += trans[tg[sl - 1] * L + STOP];

    __shared__ float red[4];
#pragma unroll
    for (int d = 1; d < 64; d <<= 1) s += __shfl_xor(s, d);
    if ((tid & 63) == 0) red[tid >> 6] = s;
    __syncthreads();
    if (tid == 0) score_out[b] = (red[0] + red[1]) + (red[2] + red[3]);
}

__global__ __launch_bounds__(128)
void crf_combine(const float* __restrict__ fwd,
                 const float* __restrict__ real,
                 float* __restrict__ out)
{
    const int tid = threadIdx.x;
    float s = fwd[tid] - real[tid];
#pragma unroll
    for (int d = 1; d < 64; d <<= 1) s += __shfl_xor(s, d);
    __shared__ float red[2];
    if ((tid & 63) == 0) red[tid >> 6] = s;
    __syncthreads();
    if (tid == 0) out[0] = red[0] + red[1];
}

extern "C" void kernel_launch(void* const* d_in, const int* in_sizes, int n_in,
                              void* d_out, int out_size, void* d_ws, size_t ws_size,
                              hipStream_t stream)
{
    const float* pred    = (const float*)d_in[0];
    const float* trans   = (const float*)d_in[1];
    const int*   tags    = (const int*)d_in[2];
    const int*   seq_len = (const int*)d_in[3];

    float* ws   = (float*)d_ws;
    float* fwd  = ws;        // 128 floats
    float* real = ws + 128;  // 128 floats

    const size_t bf16_bytes = (size_t)NBLK * 1024 * 4096; // 33.5 MB
    void* pxbuf = (char*)d_ws + 1024;

    if (ws_size >= 1024 + bf16_bytes) {
        crf_pexp<<<8192, 256, 0, stream>>>(pred, seq_len, (unsigned short*)pxbuf);
        crf_chain<1><<<4, 64, 0, stream>>>(pred, trans, seq_len, pxbuf, fwd);
    } else {
        crf_chain<0><<<NBLK, 64, 0, stream>>>(pred, trans, seq_len, nullptr, fwd);
    }
    crf_score  <<<NBATCH, 256, 0, stream>>>(pred, trans, tags, seq_len, real);
    crf_combine<<<1, 128, 0, stream>>>(fwd, real, (float*)d_out);
}

// Round 13
// 721.580 us; speedup vs baseline: 1.3267x; 1.3267x over previous
//
#include <hip/hip_runtime.h>

constexpr int L      = 128;
constexpr int TDIM   = 1024;
constexpr int NBATCH = 128;
constexpr int START  = L - 2; // 126
constexpr int STOP   = L - 1; // 127
constexpr int BSUB   = 16;
constexpr int NBLK   = NBATCH / BSUB; // 8

typedef short bf16x8 __attribute__((ext_vector_type(8)));
typedef float f32x4  __attribute__((ext_vector_type(4)));
typedef int   i32x4  __attribute__((ext_vector_type(4)));

union B4 { i32x4 i; bf16x8 v; };

__device__ __forceinline__ short f2bf(float f) {
    unsigned x = __float_as_uint(f);
    return (short)((x + 0x7fffu + ((x >> 16) & 1u)) >> 16); // RNE
}
__device__ __forceinline__ unsigned pkbf(float lo, float hi) {
    unsigned r;
    asm("v_cvt_pk_bf16_f32 %0, %1, %2" : "=v"(r) : "v"(lo), "v"(hi));
    return r;
}

// ---------------------------------------------------------------------------
// Precompute: pexp = masked bf16 exp(pred) (layout verified exact R4-R12).
// ---------------------------------------------------------------------------
__global__ __launch_bounds__(256)
void crf_pexp(const float* __restrict__ pred, const int* __restrict__ seq_len,
              unsigned short* __restrict__ pexp)
{
    int gid  = blockIdx.x * 256 + threadIdx.x;  // 2,097,152 total
    int lane = gid & 63;
    int c    = (gid >> 6) & 3;
    int row  = (gid >> 8) & 1023;
    int blk  = gid >> 18;
    int l15 = lane & 15, l4 = lane >> 4;
    int b = blk * 16 + l15;
    bool live = row < seq_len[b];

    const float* src = pred + ((size_t)b * TDIM + row) * L + 32 * c + 4 * l4;
    f32x4 v0 = *(const f32x4*)(src);
    f32x4 v1 = *(const f32x4*)(src + 16);

    float e0[4], e1[4];
#pragma unroll
    for (int r = 0; r < 4; ++r) {
        int s0 = 32 * c + 4 * l4 + r;
        int s1 = s0 + 16;
        e0[r] = (live && s0 < 126) ? __expf(v0[r]) : 0.0f;
        e1[r] = (live && s1 < 126) ? __expf(v1[r]) : 0.0f;
    }
    i32x4 out;
    out[0] = (int)pkbf(e0[0], e0[1]);
    out[1] = (int)pkbf(e0[2], e0[3]);
    out[2] = (int)pkbf(e1[0], e1[1]);
    out[3] = (int)pkbf(e1[2], e1[3]);
    *(i32x4*)((char*)pexp + (size_t)gid * 16) = out;
}

// ---------------------------------------------------------------------------
// Split chain: 8 blocks x 2 waves. Wave w owns output states 64w..64w+63
// (T = 4w+Tl). Per step: 16 MFMA + half the stage VALU per wave; the u-halves
// are exchanged via LDS planes (int plane p at [p*64 + lane], conflict-free),
// one __syncthreads per step, double-buffered. Numerics = verified path.
// ---------------------------------------------------------------------------
struct PH { i32x4 q[2]; };

__global__ __launch_bounds__(128, 1)
void crf_chain_split(const float* __restrict__ pred,
                     const float* __restrict__ trans,
                     const int* __restrict__ seq_len,
                     const unsigned short* __restrict__ pexp,
                     float* __restrict__ fwd_out)
{
    const int tid  = threadIdx.x;
    const int lane = tid & 63;
    const int w    = tid >> 6;          // 0 or 1
    const int l15 = lane & 15, l4 = lane >> 4;
    const int blk = blockIdx.x;
    const int b   = blk * BSUB + l15;

    __shared__ int lds[2 * 16 * 64 + 4]; // 2 bufs x 16 planes x 64 + flags

    // A-frags for own T = 4w+Tl: elem e = exp(trans[s][16T + l15]),
    // s = 16*kt + 64*(e>>2) + 4*l4 + (e&3)    (verified mapping)
    bf16x8 A4[4][4];
#pragma unroll
    for (int Tl = 0; Tl < 4; ++Tl)
#pragma unroll
        for (int kt = 0; kt < 4; ++kt) {
            bf16x8 v;
#pragma unroll
            for (int e = 0; e < 8; ++e) {
                int s = 16 * kt + 64 * (e >> 2) + 4 * l4 + (e & 3);
                v[e] = f2bf(__expf(trans[s * L + 16 * (4 * w + Tl) + l15]));
            }
            A4[Tl][kt] = v;
        }

    const int srow1 = seq_len[b] + 1;
    int mx = srow1;
#pragma unroll
    for (int d = 1; d < 16; d <<= 1) mx = max(mx, __shfl_xor(mx, d));
    const int tmaxR = __builtin_amdgcn_readfirstlane((mx + 1) & ~1); // even

    const f32x4 Z4 = {0.f, 0.f, 0.f, 0.f};

    B4 B[4];
#pragma unroll
    for (int kt = 0; kt < 4; ++kt) B[kt].i = (i32x4){0, 0, 0, 0};
    // u0: state 126 = T7 (wave1 Tl3), l4==3, elem6 -> own slot i[3] low half
    if (w == 1 && l4 == 3) B[3].i[3] = 0x3F80;

    float C = 0.0f;
    bool  applyScale = false;
    float res = 1.0f, resC = 0.0f;

    // P chunks for own half: chunks 2w, 2w+1 of the verified pexp layout
    const char* pxb = (const char*)pexp + ((size_t)blk << 22) + (size_t)w * 2048;
    auto loadPH = [&](PH& p, int row) {
        const char* s = pxb + (size_t)row * 4096 + (size_t)lane * 16;
        p.q[0] = *(const i32x4*)s;
        p.q[1] = *(const i32x4*)(s + 1024);
    };
    PH pa, pb_;
    loadPH(pa, 0); loadPH(pb_, 1);

    f32x4 acc[4];

    // exchange own half (B own slots) -> barrier -> read other half -> MFMA
    auto EXCH = [&](int par, int tS, bool CHK, bool myTrig) {
        int* base = lds + par * 1024 + lane;
        if (w == 0) {
#pragma unroll
            for (int kt = 0; kt < 4; ++kt) {
                base[(2 * kt + 0) * 64] = B[kt].i[0];
                base[(2 * kt + 1) * 64] = B[kt].i[1];
            }
        } else {
#pragma unroll
            for (int kt = 0; kt < 4; ++kt) {
                base[(8 + 2 * kt + 0) * 64] = B[kt].i[2];
                base[(8 + 2 * kt + 1) * 64] = B[kt].i[3];
            }
        }
        if (CHK && lane == 0 && myTrig) lds[2048 + par * 2 + w] = tS;
        __syncthreads();
        if (w == 0) {
#pragma unroll
            for (int kt = 0; kt < 4; ++kt) {
                B[kt].i[2] = base[(8 + 2 * kt + 0) * 64];
                B[kt].i[3] = base[(8 + 2 * kt + 1) * 64];
            }
        } else {
#pragma unroll
            for (int kt = 0; kt < 4; ++kt) {
                B[kt].i[0] = base[(2 * kt + 0) * 64];
                B[kt].i[1] = base[(2 * kt + 1) * 64];
            }
        }
        if (CHK) {
            int of = lds[2048 + par * 2 + (1 - w)];
            applyScale = myTrig || (of == tS);
        }
#pragma unroll
        for (int Tl = 0; Tl < 4; ++Tl)
            acc[Tl] = __builtin_amdgcn_mfma_f32_16x16x32_bf16(A4[Tl][0], B[0].v, Z4, 0, 0, 0);
#pragma unroll
        for (int kt = 1; kt < 4; ++kt)
#pragma unroll
            for (int Tl = 0; Tl < 4; ++Tl)
                acc[Tl] = __builtin_amdgcn_mfma_f32_16x16x32_bf16(A4[Tl][kt], B[kt].v, acc[Tl], 0, 0, 0);
    };

    auto ITER = [&](int tS, PH& P, bool CHK, bool SCL) {
        // extraction (STOP = wave1 acc[3][3]) before P, before C bump
        bool hit = (tS == srow1);
        res  = hit ? acc[3][3] : res;
        resC = hit ? C : resC;

        float mloc = 0.0f;
        unsigned Wd[4][2];
#pragma unroll
        for (int Tl = 0; Tl < 4; ++Tl) {
            unsigned wa = (unsigned)P.q[Tl >> 1][(Tl & 1) * 2 + 0];
            unsigned wb = (unsigned)P.q[Tl >> 1][(Tl & 1) * 2 + 1];
            float u0 = acc[Tl][0] * __uint_as_float(wa << 16);
            float u1 = acc[Tl][1] * __uint_as_float(wa & 0xffff0000u);
            float u2 = acc[Tl][2] * __uint_as_float(wb << 16);
            float u3 = acc[Tl][3] * __uint_as_float(wb & 0xffff0000u);
            if (SCL && applyScale) {
                u0 *= 0x1p-64f; u1 *= 0x1p-64f; u2 *= 0x1p-64f; u3 *= 0x1p-64f;
            }
            if (CHK)
                mloc = fmaxf(mloc, fmaxf(fmaxf(u0, u1), fmaxf(u2, u3)));
            Wd[Tl][0] = pkbf(u0, u1);
            Wd[Tl][1] = pkbf(u2, u3);
        }
        if (SCL && applyScale) { C += 44.3614195558365f; applyScale = false; }

        if (w == 0) {
#pragma unroll
            for (int kt = 0; kt < 4; ++kt) {
                B[kt].i[0] = (int)Wd[kt][0];
                B[kt].i[1] = (int)Wd[kt][1];
            }
        } else {
#pragma unroll
            for (int kt = 0; kt < 4; ++kt) {
                B[kt].i[2] = (int)Wd[kt][0];
                B[kt].i[3] = (int)Wd[kt][1];
            }
        }
        bool myTrig = CHK ? (__ballot(mloc > 0x1p80f) != 0ull) : false;
        EXCH(tS & 1, tS, CHK, myTrig);
        loadPH(P, min(tS + 1, TDIM - 1));
    };

    if (tid < 4) lds[2048 + tid] = 0;
    EXCH(0, 0, false, false);   // initial exchange + MFMA -> acc = D_1

    for (int t0 = 1; t0 < tmaxR; t0 += 2) {
        ITER(t0,     pa,  true,  false);   // check step
        ITER(t0 + 1, pb_, false, true);    // apply step
    }

    if (w == 1 && l4 == 3)
        fwd_out[b] = __logf(res) + resC;
}

// ---------------------------------------------------------------------------
// Fallback (no workspace): verified single-wave chain on raw pred.
// ---------------------------------------------------------------------------
__global__ __launch_bounds__(64, 1)
void crf_chain_fb(const float* __restrict__ pred,
                  const float* __restrict__ trans,
                  const int* __restrict__ seq_len,
                  float* __restrict__ fwd_out)
{
    const int lane = threadIdx.x;
    const int l15 = lane & 15, l4 = lane >> 4;
    const int blk = blockIdx.x;
    const int b   = blk * BSUB + l15;

    bf16x8 A[8][4];
#pragma unroll
    for (int T = 0; T < 8; ++T)
#pragma unroll
        for (int kt = 0; kt < 4; ++kt) {
            bf16x8 v;
#pragma unroll
            for (int e = 0; e < 8; ++e) {
                int s = 16 * kt + 64 * (e >> 2) + 4 * l4 + (e & 3);
                v[e] = f2bf(__expf(trans[s * L + 16 * T + l15]));
            }
            A[T][kt] = v;
        }

    const int srow1 = seq_len[b] + 1;
    int mx = srow1;
#pragma unroll
    for (int d = 1; d < 16; d <<= 1) mx = max(mx, __shfl_xor(mx, d));
    const int tmaxR = __builtin_amdgcn_readfirstlane((mx + 1) & ~1);

    B4 B[4];
#pragma unroll
    for (int kt = 0; kt < 4; ++kt) B[kt].i = (i32x4){0, 0, 0, 0};
    if (l4 == 3) B[3].i[3] = 0x3F80;

    const f32x4 Z4 = {0.f, 0.f, 0.f, 0.f};
    float C = 0.0f;
    bool  applyScale = false;
    float res = 1.0f, resC = 0.0f;

    const float* pfb = pred + (size_t)b * TDIM * L + 4 * l4;
    struct PF { f32x4 q[8]; };
    PF fa, fb;
    auto loadPF = [&](PF& p, int row) {
        const f32x4* s = (const f32x4*)(pfb + (size_t)row * L);
#pragma unroll
        for (int T = 0; T < 8; ++T) p.q[T] = s[T * 4];
    };
    loadPF(fa, 0); loadPF(fb, 1);
    f32x4 acc[8];
    auto stepF = [&](int t, PF& pf, bool chk) {
#pragma unroll
        for (int T = 0; T < 8; ++T)
            acc[T] = __builtin_amdgcn_mfma_f32_16x16x32_bf16(A[T][0], B[0].v, Z4, 0, 0, 0);
#pragma unroll
        for (int kt = 1; kt < 4; ++kt)
#pragma unroll
            for (int T = 0; T < 8; ++T)
                acc[T] = __builtin_amdgcn_mfma_f32_16x16x32_bf16(A[T][kt], B[kt].v, acc[T], 0, 0, 0);

        bool hit = (t == srow1);
        res  = hit ? acc[7][3] : res;
        resC = hit ? C : resC;

        const bool live = (t < srow1);
        float u[8][4];
#pragma unroll
        for (int T = 0; T < 8; ++T)
#pragma unroll
            for (int r = 0; r < 4; ++r) {
                bool dead = !live || (T == 7 && l4 == 3 && r >= 2);
                u[T][r] = dead ? 0.0f : acc[T][r] * __expf(pf.q[T][r]);
            }
        if (applyScale) {
#pragma unroll
            for (int T = 0; T < 8; ++T)
#pragma unroll
                for (int r = 0; r < 4; ++r) u[T][r] *= 0x1p-64f;
            C += 44.3614195558365f;
        }
        applyScale = false;
        if (chk) {
            float m[8];
#pragma unroll
            for (int T = 0; T < 8; ++T)
                m[T] = fmaxf(fmaxf(u[T][0], u[T][1]), fmaxf(u[T][2], u[T][3]));
            float mx4 = fmaxf(fmaxf(fmaxf(m[0], m[1]), fmaxf(m[2], m[3])),
                              fmaxf(fmaxf(m[4], m[5]), fmaxf(m[6], m[7])));
            applyScale = (__ballot(mx4 > 0x1p80f) != 0ull);
        }
#pragma unroll
        for (int kt = 0; kt < 4; ++kt) {
            B[kt].i[0] = (int)pkbf(u[kt][0], u[kt][1]);
            B[kt].i[1] = (int)pkbf(u[kt][2], u[kt][3]);
            B[kt].i[2] = (int)pkbf(u[kt + 4][0], u[kt + 4][1]);
            B[kt].i[3] = (int)pkbf(u[kt + 4][2], u[kt + 4][3]);
        }
        loadPF(pf, min(t + 1, TDIM - 1));
    };
    for (int t0 = 0; t0 < tmaxR; t0 += 2) {
        stepF(t0 + 1, fa, true);
        stepF(t0 + 2, fb, false);
    }
    if (l4 == 3)
        fwd_out[b] = __logf(res) + resC;
}

// ---------------------------------------------------------------------------
// Gold path score (unchanged, verified exact).
// ---------------------------------------------------------------------------
__global__ __launch_bounds__(256)
void crf_score(const float* __restrict__ pred,
               const float* __restrict__ trans,
               const int* __restrict__ tags,
               const int* __restrict__ seq_len,
               float* __restrict__ score_out)
{
    const int b = blockIdx.x;
    const int tid = threadIdx.x;
    const int sl = seq_len[b];
    const int* tg = tags + b * TDIM;

    float s = 0.0f;
    for (int t = tid; t < sl; t += 256) {
        int tag = tg[t];
        s += pred[((long)b * TDIM + t) * L + tag];
        int prev = (t == 0) ? START : tg[t - 1];
        s += trans[prev * L + tag];
    }
    if (tid == 0) s += trans[tg[sl - 1] * L + STOP];

    __shared__ float red[4];
#pragma unroll
    for (int d = 1; d < 64; d <<= 1) s += __shfl_xor(s, d);
    if ((tid & 63) == 0) red[tid >> 6] = s;
    __syncthreads();
    if (tid == 0) score_out[b] = (red[0] + red[1]) + (red[2] + red[3]);
}

__global__ __launch_bounds__(128)
void crf_combine(const float* __restrict__ fwd,
                 const float* __restrict__ real,
                 float* __restrict__ out)
{
    const int tid = threadIdx.x;
    float s = fwd[tid] - real[tid];
#pragma unroll
    for (int d = 1; d < 64; d <<= 1) s += __shfl_xor(s, d);
    __shared__ float red[2];
    if ((tid & 63) == 0) red[tid >> 6] = s;
    __syncthreads();
    if (tid == 0) out[0] = red[0] + red[1];
}

extern "C" void kernel_launch(void* const* d_in, const int* in_sizes, int n_in,
                              void* d_out, int out_size, void* d_ws, size_t ws_size,
                              hipStream_t stream)
{
    const float* pred    = (const float*)d_in[0];
    const float* trans   = (const float*)d_in[1];
    const int*   tags    = (const int*)d_in[2];
    const int*   seq_len = (const int*)d_in[3];

    float* ws   = (float*)d_ws;
    float* fwd  = ws;        // 128 floats
    float* real = ws + 128;  // 128 floats

    const size_t bf16_bytes = (size_t)NBLK * 1024 * 4096; // 33.5 MB
    void* pxbuf = (char*)d_ws + 1024;

    if (ws_size >= 1024 + bf16_bytes) {
        crf_pexp<<<8192, 256, 0, stream>>>(pred, seq_len, (unsigned short*)pxbuf);
        crf_chain_split<<<NBLK, 128, 0, stream>>>(pred, trans, seq_len,
                                                  (const unsigned short*)pxbuf, fwd);
    } else {
        crf_chain_fb<<<NBLK, 64, 0, stream>>>(pred, trans, seq_len, fwd);
    }
    crf_score  <<<NBATCH, 256, 0, stream>>>(pred, trans, tags, seq_len, real);
    crf_combine<<<1, 128, 0, stream>>>(fwd, real, (float*)d_out);
}

// Round 14
// 649.138 us; speedup vs baseline: 1.4748x; 1.1116x over previous
//
#include <hip/hip_runtime.h>

constexpr int L      = 128;
constexpr int TDIM   = 1024;
constexpr int NBATCH = 128;
constexpr int START  = L - 2; // 126
constexpr int STOP   = L - 1; // 127
constexpr int BSUB   = 16;
constexpr int NBLK   = NBATCH / BSUB; // 8

typedef short bf16x8 __attribute__((ext_vector_type(8)));
typedef float f32x4  __attribute__((ext_vector_type(4)));
typedef int   i32x4  __attribute__((ext_vector_type(4)));

union B4 { i32x4 i; bf16x8 v; };

__device__ __forceinline__ short f2bf(float f) {
    unsigned x = __float_as_uint(f);
    return (short)((x + 0x7fffu + ((x >> 16) & 1u)) >> 16); // RNE
}
__device__ __forceinline__ unsigned pkbf(float lo, float hi) {
    unsigned r;
    asm("v_cvt_pk_bf16_f32 %0, %1, %2" : "=v"(r) : "v"(lo), "v"(hi));
    return r;
}

// ---------------------------------------------------------------------------
// Precompute: pexp32 = masked f32 exp(pred), chain-lane-sequential layout.
// byte = blk*2^23 + row*8192 + T*1024 + lane*16 -> P for states 16T+4*l4+r,
// batch blk*16+l15. (Layout numerically traced against loadPX; R10/R11.)
// ---------------------------------------------------------------------------
__global__ __launch_bounds__(256)
void crf_pexp32(const float* __restrict__ pred, const int* __restrict__ seq_len,
                float* __restrict__ pexp)
{
    int gid  = blockIdx.x * 256 + threadIdx.x;  // 4,194,304 total
    int lane = gid & 63;
    int T    = (gid >> 6) & 7;
    int row  = (gid >> 9) & 1023;
    int blk  = gid >> 19;
    int l15 = lane & 15, l4 = lane >> 4;
    int b = blk * 16 + l15;
    bool live = row < seq_len[b];

    const float* src = pred + ((size_t)b * TDIM + row) * L + 16 * T + 4 * l4;
    f32x4 v = *(const f32x4*)src;
    f32x4 o;
#pragma unroll
    for (int r = 0; r < 4; ++r) {
        int s = 16 * T + 4 * l4 + r;
        o[r] = (live && s < 126) ? __expf(v[r]) : 0.0f;
    }
    *(f32x4*)((char*)pexp + (size_t)gid * 16) = o;
}

// ---------------------------------------------------------------------------
// Chain: 8 blocks x 1 wave, SINGLE non-template kernel, f32 P.
// R6 skeleton: interleaved stages/groups, every-2nd-step check, deferred
// apply, register extraction. Stage math = R6 semantics with f32 P source.
// ---------------------------------------------------------------------------
struct PF8 { f32x4 q[8]; };

#define GROUP(ACCO, KT, SEED)                                                \
  {                                                                          \
    ACCO[0] = __builtin_amdgcn_mfma_f32_16x16x32_bf16(A[0][KT], B[KT].v, (SEED) ? Z4 : ACCO[0], 0, 0, 0); \
    ACCO[4] = __builtin_amdgcn_mfma_f32_16x16x32_bf16(A[4][KT], B[KT].v, (SEED) ? Z4 : ACCO[4], 0, 0, 0); \
    ACCO[1] = __builtin_amdgcn_mfma_f32_16x16x32_bf16(A[1][KT], B[KT].v, (SEED) ? Z4 : ACCO[1], 0, 0, 0); \
    ACCO[5] = __builtin_amdgcn_mfma_f32_16x16x32_bf16(A[5][KT], B[KT].v, (SEED) ? Z4 : ACCO[5], 0, 0, 0); \
    ACCO[2] = __builtin_amdgcn_mfma_f32_16x16x32_bf16(A[2][KT], B[KT].v, (SEED) ? Z4 : ACCO[2], 0, 0, 0); \
    ACCO[6] = __builtin_amdgcn_mfma_f32_16x16x32_bf16(A[6][KT], B[KT].v, (SEED) ? Z4 : ACCO[6], 0, 0, 0); \
    ACCO[3] = __builtin_amdgcn_mfma_f32_16x16x32_bf16(A[3][KT], B[KT].v, (SEED) ? Z4 : ACCO[3], 0, 0, 0); \
    ACCO[7] = __builtin_amdgcn_mfma_f32_16x16x32_bf16(A[7][KT], B[KT].v, (SEED) ? Z4 : ACCO[7], 0, 0, 0); \
    __builtin_amdgcn_sched_group_barrier(0x008, 8, 0);                       \
  }

#define STAGE32(KT, IN, P, CHK, SCL)                                         \
  {                                                                          \
    f32x4 uA = IN[KT] * P.q[KT];                                             \
    f32x4 uB = IN[(KT) + 4] * P.q[(KT) + 4];                                 \
    if ((SCL) && applyScale) {                                               \
      uA[0] *= 0x1p-64f; uA[1] *= 0x1p-64f; uA[2] *= 0x1p-64f; uA[3] *= 0x1p-64f; \
      uB[0] *= 0x1p-64f; uB[1] *= 0x1p-64f; uB[2] *= 0x1p-64f; uB[3] *= 0x1p-64f; \
    }                                                                        \
    if (CHK) {                                                               \
      mloc4[0] = fmaxf(mloc4[0], fmaxf(uA[0], uB[0]));                       \
      mloc4[1] = fmaxf(mloc4[1], fmaxf(uA[1], uB[1]));                       \
      mloc4[2] = fmaxf(mloc4[2], fmaxf(uA[2], uB[2]));                       \
      mloc4[3] = fmaxf(mloc4[3], fmaxf(uA[3], uB[3]));                       \
    }                                                                        \
    B[KT].i[0] = (int)pkbf(uA[0], uA[1]);                                    \
    B[KT].i[1] = (int)pkbf(uA[2], uA[3]);                                    \
    B[KT].i[2] = (int)pkbf(uB[0], uB[1]);                                    \
    B[KT].i[3] = (int)pkbf(uB[2], uB[3]);                                    \
    __builtin_amdgcn_sched_group_barrier(0x002, 12, 0);                      \
  }

#define ITER32(T_, IN, OUT, P, CHK, SCL)                                     \
  {                                                                          \
    const int tS = (T_);                                                     \
    f32x4 mloc4 = Z4; (void)mloc4;                                           \
    STAGE32(0, IN, P, CHK, SCL)                                              \
    STAGE32(1, IN, P, CHK, SCL)                                              \
    GROUP(OUT, 0, true)                                                      \
    STAGE32(2, IN, P, CHK, SCL)                                              \
    GROUP(OUT, 1, false)                                                     \
    STAGE32(3, IN, P, CHK, SCL)                                              \
    { bool hit = (tS == srow1);                                              \
      res  = hit ? IN[7][3] : res;                                           \
      resC = hit ? C : resC; }                                               \
    if ((SCL) && applyScale) { C += 44.3614195558365f; applyScale = false; } \
    GROUP(OUT, 2, false)                                                     \
    GROUP(OUT, 3, false)                                                     \
    if (CHK) {                                                               \
      float hm = fmaxf(fmaxf(mloc4[0], mloc4[1]), fmaxf(mloc4[2], mloc4[3])); \
      applyScale = (__ballot(hm > 0x1p80f) != 0ull);                         \
    }                                                                        \
    loadPX(P, min(tS + 1, TDIM - 1));                                        \
  }

__global__ __launch_bounds__(64, 1)
void crf_chain32(const float* __restrict__ trans,
                 const int* __restrict__ seq_len,
                 const float* __restrict__ pexp,
                 float* __restrict__ fwd_out)
{
    const int lane = threadIdx.x;
    const int l15 = lane & 15, l4 = lane >> 4;
    const int blk = blockIdx.x;
    const int b   = blk * BSUB + l15;

    // A-frags: A[T][kt] elem e = exp(trans[s][16T + l15]),
    //          s = 16*kt + 64*(e>>2) + 4*l4 + (e&3)      (verified exact)
    bf16x8 A[8][4];
#pragma unroll
    for (int T = 0; T < 8; ++T)
#pragma unroll
        for (int kt = 0; kt < 4; ++kt) {
            bf16x8 v;
#pragma unroll
            for (int e = 0; e < 8; ++e) {
                int s = 16 * kt + 64 * (e >> 2) + 4 * l4 + (e & 3);
                v[e] = f2bf(__expf(trans[s * L + 16 * T + l15]));
            }
            A[T][kt] = v;
        }

    const int srow1 = seq_len[b] + 1;
    int mx = srow1;
#pragma unroll
    for (int d = 1; d < 16; d <<= 1) mx = max(mx, __shfl_xor(mx, d));
    const int tmaxR = __builtin_amdgcn_readfirstlane((mx + 1) & ~1); // even

    B4 B[4];
#pragma unroll
    for (int kt = 0; kt < 4; ++kt) B[kt].i = (i32x4){0, 0, 0, 0};
    if (l4 == 3) B[3].i[3] = 0x3F80;    // START = 1.0 (elem6 low half)

    const f32x4 Z4 = {0.f, 0.f, 0.f, 0.f};

    float C = 0.0f;
    bool  applyScale = false;
    float res = 1.0f, resC = 0.0f;

    const char* pxb = (const char*)pexp + ((size_t)blk << 23) + (size_t)lane * 16;
    auto loadPX = [&](PF8& p, int row) {
        const char* base = pxb + (size_t)row * 8192;
#pragma unroll
        for (int T = 0; T < 8; ++T)
            p.q[T] = *(const f32x4*)(base + T * 1024);
    };

    PF8 pa, pb_;
    loadPX(pa, 0); loadPX(pb_, 1);

    f32x4 XA[8], YA[8];
    GROUP(XA, 0, true)
    GROUP(XA, 1, false)
    GROUP(XA, 2, false)
    GROUP(XA, 3, false)

    for (int t0 = 1; t0 < tmaxR; t0 += 2) {
        ITER32(t0,     XA, YA, pa,  true,  false)   // check step
        ITER32(t0 + 1, YA, XA, pb_, false, true)    // apply step
    }

    if (l4 == 3)
        fwd_out[b] = __logf(res) + resC;
}

// ---------------------------------------------------------------------------
// Fallback (small ws): verified single-wave chain on raw pred (R12/R13 text).
// ---------------------------------------------------------------------------
__global__ __launch_bounds__(64, 1)
void crf_chain_fb(const float* __restrict__ pred,
                  const float* __restrict__ trans,
                  const int* __restrict__ seq_len,
                  float* __restrict__ fwd_out)
{
    const int lane = threadIdx.x;
    const int l15 = lane & 15, l4 = lane >> 4;
    const int blk = blockIdx.x;
    const int b   = blk * BSUB + l15;

    bf16x8 A[8][4];
#pragma unroll
    for (int T = 0; T < 8; ++T)
#pragma unroll
        for (int kt = 0; kt < 4; ++kt) {
            bf16x8 v;
#pragma unroll
            for (int e = 0; e < 8; ++e) {
                int s = 16 * kt + 64 * (e >> 2) + 4 * l4 + (e & 3);
                v[e] = f2bf(__expf(trans[s * L + 16 * T + l15]));
            }
            A[T][kt] = v;
        }

    const int srow1 = seq_len[b] + 1;
    int mx = srow1;
#pragma unroll
    for (int d = 1; d < 16; d <<= 1) mx = max(mx, __shfl_xor(mx, d));
    const int tmaxR = __builtin_amdgcn_readfirstlane((mx + 1) & ~1);

    B4 B[4];
#pragma unroll
    for (int kt = 0; kt < 4; ++kt) B[kt].i = (i32x4){0, 0, 0, 0};
    if (l4 == 3) B[3].i[3] = 0x3F80;

    const f32x4 Z4 = {0.f, 0.f, 0.f, 0.f};
    float C = 0.0f;
    bool  applyScale = false;
    float res = 1.0f, resC = 0.0f;

    const float* pfb = pred + (size_t)b * TDIM * L + 4 * l4;
    struct PF { f32x4 q[8]; };
    PF fa, fb;
    auto loadPF = [&](PF& p, int row) {
        const f32x4* s = (const f32x4*)(pfb + (size_t)row * L);
#pragma unroll
        for (int T = 0; T < 8; ++T) p.q[T] = s[T * 4];
    };
    loadPF(fa, 0); loadPF(fb, 1);
    f32x4 acc[8];
    auto stepF = [&](int t, PF& pf, bool chk) {
#pragma unroll
        for (int T = 0; T < 8; ++T)
            acc[T] = __builtin_amdgcn_mfma_f32_16x16x32_bf16(A[T][0], B[0].v, Z4, 0, 0, 0);
#pragma unroll
        for (int kt = 1; kt < 4; ++kt)
#pragma unroll
            for (int T = 0; T < 8; ++T)
                acc[T] = __builtin_amdgcn_mfma_f32_16x16x32_bf16(A[T][kt], B[kt].v, acc[T], 0, 0, 0);

        bool hit = (t == srow1);
        res  = hit ? acc[7][3] : res;
        resC = hit ? C : resC;

        const bool live = (t < srow1);
        float u[8][4];
#pragma unroll
        for (int T = 0; T < 8; ++T)
#pragma unroll
            for (int r = 0; r < 4; ++r) {
                bool dead = !live || (T == 7 && l4 == 3 && r >= 2);
                u[T][r] = dead ? 0.0f : acc[T][r] * __expf(pf.q[T][r]);
            }
        if (applyScale) {
#pragma unroll
            for (int T = 0; T < 8; ++T)
#pragma unroll
                for (int r = 0; r < 4; ++r) u[T][r] *= 0x1p-64f;
            C += 44.3614195558365f;
        }
        applyScale = false;
        if (chk) {
            float m[8];
#pragma unroll
            for (int T = 0; T < 8; ++T)
                m[T] = fmaxf(fmaxf(u[T][0], u[T][1]), fmaxf(u[T][2], u[T][3]));
            float mx4 = fmaxf(fmaxf(fmaxf(m[0], m[1]), fmaxf(m[2], m[3])),
                              fmaxf(fmaxf(m[4], m[5]), fmaxf(m[6], m[7])));
            applyScale = (__ballot(mx4 > 0x1p80f) != 0ull);
        }
#pragma unroll
        for (int kt = 0; kt < 4; ++kt) {
            B[kt].i[0] = (int)pkbf(u[kt][0], u[kt][1]);
            B[kt].i[1] = (int)pkbf(u[kt][2], u[kt][3]);
            B[kt].i[2] = (int)pkbf(u[kt + 4][0], u[kt + 4][1]);
            B[kt].i[3] = (int)pkbf(u[kt + 4][2], u[kt + 4][3]);
        }
        loadPF(pf, min(t + 1, TDIM - 1));
    };
    for (int t0 = 0; t0 < tmaxR; t0 += 2) {
        stepF(t0 + 1, fa, true);
        stepF(t0 + 2, fb, false);
    }
    if (l4 == 3)
        fwd_out[b] = __logf(res) + resC;
}

// ---------------------------------------------------------------------------
// Gold path score (unchanged, verified exact).
// ---------------------------------------------------------------------------
__global__ __launch_bounds__(256)
void crf_score(const float* __restrict__ pred,
               const float* __restrict__ trans,
               const int* __restrict__ tags,
               const int* __restrict__ seq_len,
               float* __restrict__ score_out)
{
    const int b = blockIdx.x;
    const int tid = threadIdx.x;
    const int sl = seq_len[b];
    const int* tg = tags + b * TDIM;

    float s = 0.0f;
    for (int t = tid; t < sl; t += 256) {
        int tag = tg[t];
        s += pred[((long)b * TDIM + t) * L + tag];
        int prev = (t == 0) ? START : tg[t - 1];
        s += trans[prev * L + tag];
    }
    if (tid == 0) s += trans[tg[sl - 1] * L + STOP];

    __shared__ float red[4];
#pragma unroll
    for (int d = 1; d < 64; d <<= 1) s += __shfl_xor(s, d);
    if ((tid & 63) == 0) red[tid >> 6] = s;
    __syncthreads();
    if (tid == 0) score_out[b] = (red[0] + red[1]) + (red[2] + red[3]);
}

__global__ __launch_bounds__(128)
void crf_combine(const float* __restrict__ fwd,
                 const float* __restrict__ real,
                 float* __restrict__ out)
{
    const int tid = threadIdx.x;
    float s = fwd[tid] - real[tid];
#pragma unroll
    for (int d = 1; d < 64; d <<= 1) s += __shfl_xor(s, d);
    __shared__ float red[2];
    if ((tid & 63) == 0) red[tid >> 6] = s;
    __syncthreads();
    if (tid == 0) out[0] = red[0] + red[1];
}

extern "C" void kernel_launch(void* const* d_in, const int* in_sizes, int n_in,
                              void* d_out, int out_size, void* d_ws, size_t ws_size,
                              hipStream_t stream)
{
    const float* pred    = (const float*)d_in[0];
    const float* trans   = (const float*)d_in[1];
    const int*   tags    = (const int*)d_in[2];
    const int*   seq_len = (const int*)d_in[3];

    float* ws   = (float*)d_ws;
    float* fwd  = ws;        // 128 floats
    float* real = ws + 128;  // 128 floats

    const size_t f32_bytes = (size_t)NBLK * 1024 * 8192; // 64 MiB
    void* pxbuf = (char*)d_ws + 1024;

    if (ws_size >= 1024 + f32_bytes) {
        crf_pexp32<<<16384, 256, 0, stream>>>(pred, seq_len, (float*)pxbuf);
        crf_chain32<<<NBLK, 64, 0, stream>>>(trans, seq_len, (const float*)pxbuf, fwd);
    } else {
        crf_chain_fb<<<NBLK, 64, 0, stream>>>(pred, trans, seq_len, fwd);
    }
    crf_score  <<<NBATCH, 256, 0, stream>>>(pred, trans, tags, seq_len, real);
    crf_combine<<<1, 128, 0, stream>>>(fwd, real, (float*)d_out);
}

// Round 15
// 627.966 us; speedup vs baseline: 1.5245x; 1.0337x over previous
//
#include <hip/hip_runtime.h>

constexpr int L      = 128;
constexpr int TDIM   = 1024;
constexpr int NBATCH = 128;
constexpr int START  = L - 2; // 126
constexpr int STOP   = L - 1; // 127
constexpr int BSUB   = 16;
constexpr int NBLK   = NBATCH / BSUB; // 8

typedef short bf16x8 __attribute__((ext_vector_type(8)));
typedef float f32x4  __attribute__((ext_vector_type(4)));
typedef int   i32x4  __attribute__((ext_vector_type(4)));

union B4 { i32x4 i; bf16x8 v; };

__device__ __forceinline__ short f2bf(float f) {
    unsigned x = __float_as_uint(f);
    return (short)((x + 0x7fffu + ((x >> 16) & 1u)) >> 16); // RNE
}
__device__ __forceinline__ unsigned pkbf(float lo, float hi) {
    unsigned r;
    asm("v_cvt_pk_bf16_f32 %0, %1, %2" : "=v"(r) : "v"(lo), "v"(hi));
    return r;
}

// ---------------------------------------------------------------------------
// Precompute: pexp = masked bf16 exp(pred) (layout verified exact R4-R14).
// ---------------------------------------------------------------------------
__global__ __launch_bounds__(256)
void crf_pexp(const float* __restrict__ pred, const int* __restrict__ seq_len,
              unsigned short* __restrict__ pexp)
{
    int gid  = blockIdx.x * 256 + threadIdx.x;  // 2,097,152 total
    int lane = gid & 63;
    int c    = (gid >> 6) & 3;
    int row  = (gid >> 8) & 1023;
    int blk  = gid >> 18;
    int l15 = lane & 15, l4 = lane >> 4;
    int b = blk * 16 + l15;
    bool live = row < seq_len[b];

    const float* src = pred + ((size_t)b * TDIM + row) * L + 32 * c + 4 * l4;
    f32x4 v0 = *(const f32x4*)(src);
    f32x4 v1 = *(const f32x4*)(src + 16);

    float e0[4], e1[4];
#pragma unroll
    for (int r = 0; r < 4; ++r) {
        int s0 = 32 * c + 4 * l4 + r;
        int s1 = s0 + 16;
        e0[r] = (live && s0 < 126) ? __expf(v0[r]) : 0.0f;
        e1[r] = (live && s1 < 126) ? __expf(v1[r]) : 0.0f;
    }
    i32x4 out;
    out[0] = (int)pkbf(e0[0], e0[1]);
    out[1] = (int)pkbf(e0[2], e0[3]);
    out[2] = (int)pkbf(e1[0], e1[1]);
    out[3] = (int)pkbf(e1[2], e1[3]);
    *(i32x4*)((char*)pexp + (size_t)gid * 16) = out;
}

// ---------------------------------------------------------------------------
// Chain: 8 blocks x 1 wave, bf16 P (verified). BRANCHLESS step + fine-grained
// MFMA:VALU sched_group interleave ({M,1}{V,3} x32) so VALU issues inside the
// matrix-pipe backpressure gaps of the in-order wave.
// ---------------------------------------------------------------------------
struct PB { i32x4 c[4]; };

#define SGBX(m, n) __builtin_amdgcn_sched_group_barrier(m, n, 0)
#define MM1 { SGBX(0x008, 1); SGBX(0x002, 3); }
#define MM4  MM1 MM1 MM1 MM1
#define MM16 MM4 MM4 MM4 MM4

// MFMA group kt: T issue order 0,4,1,5,2,6,3,7 (verified)
#define GRP(ACCO, KT, SEED)                                                  \
  {                                                                          \
    ACCO[0] = __builtin_amdgcn_mfma_f32_16x16x32_bf16(A[0][KT], B[KT].v, (SEED) ? Z4 : ACCO[0], 0, 0, 0); \
    ACCO[4] = __builtin_amdgcn_mfma_f32_16x16x32_bf16(A[4][KT], B[KT].v, (SEED) ? Z4 : ACCO[4], 0, 0, 0); \
    ACCO[1] = __builtin_amdgcn_mfma_f32_16x16x32_bf16(A[1][KT], B[KT].v, (SEED) ? Z4 : ACCO[1], 0, 0, 0); \
    ACCO[5] = __builtin_amdgcn_mfma_f32_16x16x32_bf16(A[5][KT], B[KT].v, (SEED) ? Z4 : ACCO[5], 0, 0, 0); \
    ACCO[2] = __builtin_amdgcn_mfma_f32_16x16x32_bf16(A[2][KT], B[KT].v, (SEED) ? Z4 : ACCO[2], 0, 0, 0); \
    ACCO[6] = __builtin_amdgcn_mfma_f32_16x16x32_bf16(A[6][KT], B[KT].v, (SEED) ? Z4 : ACCO[6], 0, 0, 0); \
    ACCO[3] = __builtin_amdgcn_mfma_f32_16x16x32_bf16(A[3][KT], B[KT].v, (SEED) ? Z4 : ACCO[3], 0, 0, 0); \
    ACCO[7] = __builtin_amdgcn_mfma_f32_16x16x32_bf16(A[7][KT], B[KT].v, (SEED) ? Z4 : ACCO[7], 0, 0, 0); \
  }

// Stage (TA,TB): verified R6 word-extract math, sfac applied unconditionally.
#define STG(TA, TB, AIN, PBUF, CHK)                                          \
  {                                                                          \
    unsigned wa0 = (unsigned)PBUF.c[(TA) >> 1][((TA) & 1) * 2 + 0];          \
    unsigned wa1 = (unsigned)PBUF.c[(TA) >> 1][((TA) & 1) * 2 + 1];          \
    unsigned wb0 = (unsigned)PBUF.c[(TB) >> 1][((TB) & 1) * 2 + 0];          \
    unsigned wb1 = (unsigned)PBUF.c[(TB) >> 1][((TB) & 1) * 2 + 1];          \
    float ua0 = AIN[TA][0] * __uint_as_float(wa0 << 16) * sfac;              \
    float ua1 = AIN[TA][1] * __uint_as_float(wa0 & 0xffff0000u) * sfac;      \
    float ua2 = AIN[TA][2] * __uint_as_float(wa1 << 16) * sfac;              \
    float ua3 = AIN[TA][3] * __uint_as_float(wa1 & 0xffff0000u) * sfac;      \
    float ub0 = AIN[TB][0] * __uint_as_float(wb0 << 16) * sfac;              \
    float ub1 = AIN[TB][1] * __uint_as_float(wb0 & 0xffff0000u) * sfac;      \
    float ub2 = AIN[TB][2] * __uint_as_float(wb1 << 16) * sfac;              \
    float ub3 = AIN[TB][3] * __uint_as_float(wb1 & 0xffff0000u) * sfac;      \
    if (CHK) {                                                               \
      mloc = fmaxf(mloc, fmaxf(fmaxf(fmaxf(ua0, ua1), fmaxf(ua2, ua3)),      \
                               fmaxf(fmaxf(ub0, ub1), fmaxf(ub2, ub3))));    \
    }                                                                        \
    B[TA].i[0] = (int)pkbf(ua0, ua1);                                        \
    B[TA].i[1] = (int)pkbf(ua2, ua3);                                        \
    B[TA].i[2] = (int)pkbf(ub0, ub1);                                        \
    B[TA].i[3] = (int)pkbf(ub2, ub3);                                        \
  }

// One branchless step + fine-mix directive chain.
// CHK iter: measure trigger, set sfac/cadd for next iter.
// RESETP iter (apply): consume sfac/cadd, then reset to identity.
#define ITER(T_, AIN, AOUT, PBUF, CHK, RESETP)                               \
  {                                                                          \
    const int tS = (T_);                                                     \
    float mloc = 0.0f; (void)mloc;                                           \
    STG(0, 4, AIN, PBUF, CHK)                                                \
    STG(1, 5, AIN, PBUF, CHK)                                                \
    GRP(AOUT, 0, true)                                                       \
    STG(2, 6, AIN, PBUF, CHK)                                                \
    GRP(AOUT, 1, false)                                                      \
    STG(3, 7, AIN, PBUF, CHK)                                                \
    { bool hit = (tS == srow1);                                              \
      res  = hit ? AIN[7][3] : res;                                          \
      resC = hit ? C : resC; }                                               \
    C += cadd;                                                               \
    GRP(AOUT, 2, false)                                                      \
    GRP(AOUT, 3, false)                                                      \
    if (CHK) {                                                               \
      bool trig = (__ballot(mloc > 0x1p80f) != 0ull);                        \
      sfac = trig ? 0x1p-64f : 1.0f;                                         \
      cadd = trig ? 44.3614195558365f : 0.0f;                                \
    }                                                                        \
    if (RESETP) { sfac = 1.0f; cadd = 0.0f; }                                \
    loadPB(PBUF, min(tS + 1, TDIM - 1));                                     \
    SGBX(0x002, 28);                                                         \
    MM16                                                                     \
    SGBX(0x020, 2);                                                          \
    MM16                                                                     \
    SGBX(0x020, 2);                                                          \
    SGBX(0x002, 40);                                                         \
  }

__global__ __launch_bounds__(64, 1)
void crf_chain(const float* __restrict__ trans,
               const int* __restrict__ seq_len,
               const unsigned short* __restrict__ pexp,
               float* __restrict__ fwd_out)
{
    const int lane = threadIdx.x;
    const int l15 = lane & 15, l4 = lane >> 4;
    const int blk = blockIdx.x;
    const int b   = blk * BSUB + l15;

    // A-frags: A[T][kt] elem e = exp(trans[s][16T + l15]),
    //          s = 16*kt + 64*(e>>2) + 4*l4 + (e&3)      (verified exact)
    bf16x8 A[8][4];
#pragma unroll
    for (int T = 0; T < 8; ++T)
#pragma unroll
        for (int kt = 0; kt < 4; ++kt) {
            bf16x8 v;
#pragma unroll
            for (int e = 0; e < 8; ++e) {
                int s = 16 * kt + 64 * (e >> 2) + 4 * l4 + (e & 3);
                v[e] = f2bf(__expf(trans[s * L + 16 * T + l15]));
            }
            A[T][kt] = v;
        }

    const int srow1 = seq_len[b] + 1;
    int mx = srow1;
#pragma unroll
    for (int d = 1; d < 16; d <<= 1) mx = max(mx, __shfl_xor(mx, d));
    const int tmaxR = __builtin_amdgcn_readfirstlane((mx + 1) & ~1); // even

    B4 B[4];
#pragma unroll
    for (int kt = 0; kt < 4; ++kt) B[kt].i = (i32x4){0, 0, 0, 0};
    if (l4 == 3) B[3].i[3] = 0x3F80;    // START = 1.0 (elem6 low half)

    const f32x4 Z4 = {0.f, 0.f, 0.f, 0.f};

    float C = 0.0f;
    float sfac = 1.0f, cadd = 0.0f;
    float res = 1.0f, resC = 0.0f;

    const char* pxb = (const char*)pexp + ((size_t)blk << 22);
    auto loadPB = [&](PB& p, int row) {
        const i32x4* s = (const i32x4*)(pxb + (size_t)row * 4096) + lane;
        p.c[0] = s[0]; p.c[1] = s[64]; p.c[2] = s[128]; p.c[3] = s[192];
    };

    PB pa, pb_;
    loadPB(pa, 0); loadPB(pb_, 1);

    f32x4 XA[8], YA[8];
    GRP(XA, 0, true)
    GRP(XA, 1, false)
    GRP(XA, 2, false)
    GRP(XA, 3, false)

    for (int t0 = 1; t0 < tmaxR; t0 += 2) {
        ITER(t0,     XA, YA, pa,  true,  false)   // check step
        ITER(t0 + 1, YA, XA, pb_, false, true)    // apply step
    }

    if (l4 == 3)
        fwd_out[b] = __logf(res) + resC;
}

// ---------------------------------------------------------------------------
// Fallback (small ws): verified single-wave chain on raw pred (R12/R13 text).
// ---------------------------------------------------------------------------
__global__ __launch_bounds__(64, 1)
void crf_chain_fb(const float* __restrict__ pred,
                  const float* __restrict__ trans,
                  const int* __restrict__ seq_len,
                  float* __restrict__ fwd_out)
{
    const int lane = threadIdx.x;
    const int l15 = lane & 15, l4 = lane >> 4;
    const int blk = blockIdx.x;
    const int b   = blk * BSUB + l15;

    bf16x8 A[8][4];
#pragma unroll
    for (int T = 0; T < 8; ++T)
#pragma unroll
        for (int kt = 0; kt < 4; ++kt) {
            bf16x8 v;
#pragma unroll
            for (int e = 0; e < 8; ++e) {
                int s = 16 * kt + 64 * (e >> 2) + 4 * l4 + (e & 3);
                v[e] = f2bf(__expf(trans[s * L + 16 * T + l15]));
            }
            A[T][kt] = v;
        }

    const int srow1 = seq_len[b] + 1;
    int mx = srow1;
#pragma unroll
    for (int d = 1; d < 16; d <<= 1) mx = max(mx, __shfl_xor(mx, d));
    const int tmaxR = __builtin_amdgcn_readfirstlane((mx + 1) & ~1);

    B4 B[4];
#pragma unroll
    for (int kt = 0; kt < 4; ++kt) B[kt].i = (i32x4){0, 0, 0, 0};
    if (l4 == 3) B[3].i[3] = 0x3F80;

    const f32x4 Z4 = {0.f, 0.f, 0.f, 0.f};
    float C = 0.0f;
    bool  applyScale = false;
    float res = 1.0f, resC = 0.0f;

    const float* pfb = pred + (size_t)b * TDIM * L + 4 * l4;
    struct PF { f32x4 q[8]; };
    PF fa, fb;
    auto loadPF = [&](PF& p, int row) {
        const f32x4* s = (const f32x4*)(pfb + (size_t)row * L);
#pragma unroll
        for (int T = 0; T < 8; ++T) p.q[T] = s[T * 4];
    };
    loadPF(fa, 0); loadPF(fb, 1);
    f32x4 acc[8];
    auto stepF = [&](int t, PF& pf, bool chk) {
#pragma unroll
        for (int T = 0; T < 8; ++T)
            acc[T] = __builtin_amdgcn_mfma_f32_16x16x32_bf16(A[T][0], B[0].v, Z4, 0, 0, 0);
#pragma unroll
        for (int kt = 1; kt < 4; ++kt)
#pragma unroll
            for (int T = 0; T < 8; ++T)
                acc[T] = __builtin_amdgcn_mfma_f32_16x16x32_bf16(A[T][kt], B[kt].v, acc[T], 0, 0, 0);

        bool hit = (t == srow1);
        res  = hit ? acc[7][3] : res;
        resC = hit ? C : resC;

        const bool live = (t < srow1);
        float u[8][4];
#pragma unroll
        for (int T = 0; T < 8; ++T)
#pragma unroll
            for (int r = 0; r < 4; ++r) {
                bool dead = !live || (T == 7 && l4 == 3 && r >= 2);
                u[T][r] = dead ? 0.0f : acc[T][r] * __expf(pf.q[T][r]);
            }
        if (applyScale) {
#pragma unroll
            for (int T = 0; T < 8; ++T)
#pragma unroll
                for (int r = 0; r < 4; ++r) u[T][r] *= 0x1p-64f;
            C += 44.3614195558365f;
        }
        applyScale = false;
        if (chk) {
            float m[8];
#pragma unroll
            for (int T = 0; T < 8; ++T)
                m[T] = fmaxf(fmaxf(u[T][0], u[T][1]), fmaxf(u[T][2], u[T][3]));
            float mx4 = fmaxf(fmaxf(fmaxf(m[0], m[1]), fmaxf(m[2], m[3])),
                              fmaxf(fmaxf(m[4], m[5]), fmaxf(m[6], m[7])));
            applyScale = (__ballot(mx4 > 0x1p80f) != 0ull);
        }
#pragma unroll
        for (int kt = 0; kt < 4; ++kt) {
            B[kt].i[0] = (int)pkbf(u[kt][0], u[kt][1]);
            B[kt].i[1] = (int)pkbf(u[kt][2], u[kt][3]);
            B[kt].i[2] = (int)pkbf(u[kt + 4][0], u[kt + 4][1]);
            B[kt].i[3] = (int)pkbf(u[kt + 4][2], u[kt + 4][3]);
        }
        loadPF(pf, min(t + 1, TDIM - 1));
    };
    for (int t0 = 0; t0 < tmaxR; t0 += 2) {
        stepF(t0 + 1, fa, true);
        stepF(t0 + 2, fb, false);
    }
    if (l4 == 3)
        fwd_out[b] = __logf(res) + resC;
}

// ---------------------------------------------------------------------------
// Gold path score (unchanged, verified exact).
// ---------------------------------------------------------------------------
__global__ __launch_bounds__(256)
void crf_score(const float* __restrict__ pred,
               const float* __restrict__ trans,
               const int* __restrict__ tags,
               const int* __restrict__ seq_len,
               float* __restrict__ score_out)
{
    const int b = blockIdx.x;
    const int tid = threadIdx.x;
    const int sl = seq_len[b];
    const int* tg = tags + b * TDIM;

    float s = 0.0f;
    for (int t = tid; t < sl; t += 256) {
        int tag = tg[t];
        s += pred[((long)b * TDIM + t) * L + tag];
        int prev = (t == 0) ? START : tg[t - 1];
        s += trans[prev * L + tag];
    }
    if (tid == 0) s += trans[tg[sl - 1] * L + STOP];

    __shared__ float red[4];
#pragma unroll
    for (int d = 1; d < 64; d <<= 1) s += __shfl_xor(s, d);
    if ((tid & 63) == 0) red[tid >> 6] = s;
    __syncthreads();
    if (tid == 0) score_out[b] = (red[0] + red[1]) + (red[2] + red[3]);
}

__global__ __launch_bounds__(128)
void crf_combine(const float* __restrict__ fwd,
                 const float* __restrict__ real,
                 float* __restrict__ out)
{
    const int tid = threadIdx.x;
    float s = fwd[tid] - real[tid];
#pragma unroll
    for (int d = 1; d < 64; d <<= 1) s += __shfl_xor(s, d);
    __shared__ float red[2];
    if ((tid & 63) == 0) red[tid >> 6] = s;
    __syncthreads();
    if (tid == 0) out[0] = red[0] + red[1];
}

extern "C" void kernel_launch(void* const* d_in, const int* in_sizes, int n_in,
                              void* d_out, int out_size, void* d_ws, size_t ws_size,
                              hipStream_t stream)
{
    const float* pred    = (const float*)d_in[0];
    const float* trans   = (const float*)d_in[1];
    const int*   tags    = (const int*)d_in[2];
    const int*   seq_len = (const int*)d_in[3];

    float* ws   = (float*)d_ws;
    float* fwd  = ws;        // 128 floats
    float* real = ws + 128;  // 128 floats

    const size_t bf16_bytes = (size_t)NBLK * 1024 * 4096; // 33.5 MB
    void* pxbuf = (char*)d_ws + 1024;

    if (ws_size >= 1024 + bf16_bytes) {
        crf_pexp<<<8192, 256, 0, stream>>>(pred, seq_len, (unsigned short*)pxbuf);
        crf_chain<<<NBLK, 64, 0, stream>>>(trans, seq_len,
                                           (const unsigned short*)pxbuf, fwd);
    } else {
        crf_chain_fb<<<NBLK, 64, 0, stream>>>(pred, trans, seq_len, fwd);
    }
    crf_score  <<<NBATCH, 256, 0, stream>>>(pred, trans, tags, seq_len, real);
    crf_combine<<<1, 128, 0, stream>>>(fwd, real, (float*)d_out);
}

// Round 16
// 480.319 us; speedup vs baseline: 1.9931x; 1.3074x over previous
//
#include <hip/hip_runtime.h>

constexpr int L      = 128;
constexpr int TDIM   = 1024;
constexpr int NBATCH = 128;
constexpr int START  = L - 2; // 126
constexpr int STOP   = L - 1; // 127
constexpr int BSUB   = 16;    // batches per wave (one wave per block)
constexpr int NBLK   = NBATCH / BSUB; // 8

typedef short bf16x8 __attribute__((ext_vector_type(8)));
typedef float f32x4  __attribute__((ext_vector_type(4)));
typedef int   i32x4  __attribute__((ext_vector_type(4)));

union B4 { i32x4 i; bf16x8 v; };

__device__ __forceinline__ short f2bf(float f) {
    unsigned x = __float_as_uint(f);
    return (short)((x + 0x7fffu + ((x >> 16) & 1u)) >> 16); // RNE
}
__device__ __forceinline__ unsigned pkbf(float lo, float hi) {
    unsigned r;
    asm("v_cvt_pk_bf16_f32 %0, %1, %2" : "=v"(r) : "v"(lo), "v"(hi));
    return r;
}

// ---------------------------------------------------------------------------
// Precompute: pexp = masked bf16 exp(pred), chain-lane-sequential layout.
// byte addr = ((blk*1024 + row)*4 + c)*1024 + lane*16   (verified exact)
// ---------------------------------------------------------------------------
__global__ __launch_bounds__(256)
void crf_pexp(const float* __restrict__ pred, const int* __restrict__ seq_len,
              unsigned short* __restrict__ pexp)
{
    int gid  = blockIdx.x * 256 + threadIdx.x;  // 2,097,152 total
    int lane = gid & 63;
    int c    = (gid >> 6) & 3;
    int row  = (gid >> 8) & 1023;
    int blk  = gid >> 18;
    int l15 = lane & 15, l4 = lane >> 4;
    int b = blk * 16 + l15;
    bool live = row < seq_len[b];

    const float* src = pred + ((size_t)b * TDIM + row) * L + 32 * c + 4 * l4;
    f32x4 v0 = *(const f32x4*)(src);        // T = 2c
    f32x4 v1 = *(const f32x4*)(src + 16);   // T = 2c+1

    float e0[4], e1[4];
#pragma unroll
    for (int r = 0; r < 4; ++r) {
        int s0 = 32 * c + 4 * l4 + r;
        int s1 = s0 + 16;
        e0[r] = (live && s0 < 126) ? __expf(v0[r]) : 0.0f;
        e1[r] = (live && s1 < 126) ? __expf(v1[r]) : 0.0f;
    }
    i32x4 out;
    out[0] = (int)pkbf(e0[0], e0[1]);
    out[1] = (int)pkbf(e0[2], e0[3]);
    out[2] = (int)pkbf(e1[0], e1[1]);
    out[3] = (int)pkbf(e1[2], e1[3]);
    *(i32x4*)((char*)pexp + (size_t)gid * 16) = out;
}

// ---------------------------------------------------------------------------
// Chain: 8 blocks x 1 wave. Software-pipelined at kt granularity:
// stages (unpack step t -> pack B) interleave with MFMA groups (step t+1).
// Order per iteration: [s0][s1][g0][s2][g1][s3][g2][g3].
// ---------------------------------------------------------------------------
struct PB { i32x4 c[4]; };   // one step's pexp chunk (4 x dwordx4 per lane)
struct PF { f32x4 q[8]; };   // fallback: raw pred row

// stage TA (=kt), TB (=kt+4): unpack ACCIN[TA],[TB] * P -> pack B[TA]
#define STAGE(TA, TB, ACCIN, PBUF, CHK, SCL)                                 \
  {                                                                          \
    unsigned wa0 = (unsigned)PBUF.c[(TA) >> 1][((TA) & 1) * 2 + 0];          \
    unsigned wa1 = (unsigned)PBUF.c[(TA) >> 1][((TA) & 1) * 2 + 1];          \
    unsigned wb0 = (unsigned)PBUF.c[(TB) >> 1][((TB) & 1) * 2 + 0];          \
    unsigned wb1 = (unsigned)PBUF.c[(TB) >> 1][((TB) & 1) * 2 + 1];          \
    float ua0 = ACCIN[TA][0] * __uint_as_float(wa0 << 16);                   \
    float ua1 = ACCIN[TA][1] * __uint_as_float(wa0 & 0xffff0000u);           \
    float ua2 = ACCIN[TA][2] * __uint_as_float(wa1 << 16);                   \
    float ua3 = ACCIN[TA][3] * __uint_as_float(wa1 & 0xffff0000u);           \
    float ub0 = ACCIN[TB][0] * __uint_as_float(wb0 << 16);                   \
    float ub1 = ACCIN[TB][1] * __uint_as_float(wb0 & 0xffff0000u);           \
    float ub2 = ACCIN[TB][2] * __uint_as_float(wb1 << 16);                   \
    float ub3 = ACCIN[TB][3] * __uint_as_float(wb1 & 0xffff0000u);           \
    if ((SCL) && applyScale) {                                               \
      ua0 *= 0x1p-64f; ua1 *= 0x1p-64f; ua2 *= 0x1p-64f; ua3 *= 0x1p-64f;    \
      ub0 *= 0x1p-64f; ub1 *= 0x1p-64f; ub2 *= 0x1p-64f; ub3 *= 0x1p-64f;    \
    }                                                                        \
    if (CHK) {                                                               \
      mloc = fmaxf(mloc, fmaxf(fmaxf(fmaxf(ua0, ua1), fmaxf(ua2, ua3)),      \
                               fmaxf(fmaxf(ub0, ub1), fmaxf(ub2, ub3))));    \
    }                                                                        \
    B[TA].i[0] = (int)pkbf(ua0, ua1);                                        \
    B[TA].i[1] = (int)pkbf(ua2, ua3);                                        \
    B[TA].i[2] = (int)pkbf(ub0, ub1);                                        \
    B[TA].i[3] = (int)pkbf(ub2, ub3);                                        \
    __builtin_amdgcn_sched_group_barrier(0x002, 20, 0);                      \
  }

// MFMA group kt: T issue order 0,4,1,5,2,6,3,7 (finalize acc[0],acc[4] first)
#define GROUP(ACCO, KT, SEED)                                                \
  {                                                                          \
    ACCO[0] = __builtin_amdgcn_mfma_f32_16x16x32_bf16(A[0][KT], B[KT].v, (SEED) ? Z4 : ACCO[0], 0, 0, 0); \
    ACCO[4] = __builtin_amdgcn_mfma_f32_16x16x32_bf16(A[4][KT], B[KT].v, (SEED) ? Z4 : ACCO[4], 0, 0, 0); \
    ACCO[1] = __builtin_amdgcn_mfma_f32_16x16x32_bf16(A[1][KT], B[KT].v, (SEED) ? Z4 : ACCO[1], 0, 0, 0); \
    ACCO[5] = __builtin_amdgcn_mfma_f32_16x16x32_bf16(A[5][KT], B[KT].v, (SEED) ? Z4 : ACCO[5], 0, 0, 0); \
    ACCO[2] = __builtin_amdgcn_mfma_f32_16x16x32_bf16(A[2][KT], B[KT].v, (SEED) ? Z4 : ACCO[2], 0, 0, 0); \
    ACCO[6] = __builtin_amdgcn_mfma_f32_16x16x32_bf16(A[6][KT], B[KT].v, (SEED) ? Z4 : ACCO[6], 0, 0, 0); \
    ACCO[3] = __builtin_amdgcn_mfma_f32_16x16x32_bf16(A[3][KT], B[KT].v, (SEED) ? Z4 : ACCO[3], 0, 0, 0); \
    ACCO[7] = __builtin_amdgcn_mfma_f32_16x16x32_bf16(A[7][KT], B[KT].v, (SEED) ? Z4 : ACCO[7], 0, 0, 0); \
    __builtin_amdgcn_sched_group_barrier(0x008, 8, 0);                       \
  }

// One pipelined iteration: unpack step tS (ACCIN) -> B; MFMA step tS+1 (ACCOUT)
#define ITER(T_, ACCIN, ACCOUT, PBUF, CHK, SCL)                              \
  {                                                                          \
    const int tS = (T_);                                                     \
    float mloc = 0.0f; (void)mloc;                                           \
    STAGE(0, 4, ACCIN, PBUF, CHK, SCL)                                       \
    STAGE(1, 5, ACCIN, PBUF, CHK, SCL)                                       \
    GROUP(ACCOUT, 0, true)                                                   \
    STAGE(2, 6, ACCIN, PBUF, CHK, SCL)                                       \
    GROUP(ACCOUT, 1, false)                                                  \
    STAGE(3, 7, ACCIN, PBUF, CHK, SCL)                                       \
    { bool hit = (tS == srow1);                                              \
      res  = hit ? ACCIN[7][3] : res;                                        \
      resC = hit ? C : resC; }                                               \
    if ((SCL) && applyScale) { C += 44.3614195558365f; applyScale = false; } \
    GROUP(ACCOUT, 2, false)                                                  \
    GROUP(ACCOUT, 3, false)                                                  \
    if (CHK) applyScale = (__ballot(mloc > 0x1p80f) != 0ull);                \
    loadPB(PBUF, min(tS + 1, TDIM - 1));                                     \
  }

template<bool PEXP>
__global__ __launch_bounds__(64, 1)
void crf_chain(const float* __restrict__ pred,
               const float* __restrict__ trans,
               const int* __restrict__ seq_len,
               const unsigned short* __restrict__ pexp,
               float* __restrict__ fwd_out)
{
    const int lane = threadIdx.x;
    const int l15 = lane & 15, l4 = lane >> 4;
    const int blk = blockIdx.x;
    const int b   = blk * BSUB + l15;

    // A-frags: A[T][kt] elem e = exp(trans[s][16T + l15]),
    //          s = 16*kt + 64*(e>>2) + 4*l4 + (e&3)      (verified exact)
    bf16x8 A[8][4];
#pragma unroll
    for (int T = 0; T < 8; ++T)
#pragma unroll
        for (int kt = 0; kt < 4; ++kt) {
            bf16x8 v;
#pragma unroll
            for (int e = 0; e < 8; ++e) {
                int s = 16 * kt + 64 * (e >> 2) + 4 * l4 + (e & 3);
                v[e] = f2bf(__expf(trans[s * L + 16 * T + l15]));
            }
            A[T][kt] = v;
        }

    const int srow1 = seq_len[b] + 1;

    int mx = srow1;
#pragma unroll
    for (int d = 1; d < 16; d <<= 1) mx = max(mx, __shfl_xor(mx, d));
    const int tmaxR = __builtin_amdgcn_readfirstlane((mx + 1) & ~1); // even

    B4 B[4];
#pragma unroll
    for (int kt = 0; kt < 4; ++kt) B[kt].i = (i32x4){0, 0, 0, 0};
    if (l4 == 3) B[3].i[3] = 0x3F80;    // START = 1.0 (elem6 low half)

    const f32x4 Z4 = {0.f, 0.f, 0.f, 0.f};   // persistent zero C-operand

    float C = 0.0f;
    bool  applyScale = false;
    float res = 1.0f, resC = 0.0f;

    const char*  pxb = (const char*)pexp + (size_t)blk * 1024 * 4096;
    const float* pfb = pred + (size_t)b * TDIM * L + 4 * l4;

    auto loadPB = [&](PB& p, int row) {
        const i32x4* s = (const i32x4*)(pxb + (size_t)row * 4096) + lane;
        p.c[0] = s[0]; p.c[1] = s[64]; p.c[2] = s[128]; p.c[3] = s[192];
    };
    auto loadPF = [&](PF& p, int row) {
        const f32x4* s = (const f32x4*)(pfb + (size_t)row * L);
#pragma unroll
        for (int T = 0; T < 8; ++T) p.q[T] = s[T * 4];
    };

    if constexpr (PEXP) {
        PB pa, pb_;
        loadPB(pa, 0); loadPB(pb_, 1);

        f32x4 accX[8], accY[8];
        // Prologue: accX = D_1 = A @ B_1 (B_1 = packed u0)
        GROUP(accX, 0, true)
        GROUP(accX, 1, false)
        GROUP(accX, 2, false)
        GROUP(accX, 3, false)

        for (int t0 = 1; t0 < tmaxR; t0 += 2) {
            ITER(t0,     accX, accY, pa,  true,  false)   // check step
            ITER(t0 + 1, accY, accX, pb_, false, true)    // apply step
        }
    } else {
        // Fallback (no workspace): R6-style serialized steps on raw pred.
        PF fa, fb;
        loadPF(fa, 0); loadPF(fb, 1);
        f32x4 acc[8];
        auto stepF = [&](int t, PF& pf, bool chk) {
#pragma unroll
            for (int T = 0; T < 8; ++T)
                acc[T] = __builtin_amdgcn_mfma_f32_16x16x32_bf16(A[T][0], B[0].v, Z4, 0, 0, 0);
#pragma unroll
            for (int kt = 1; kt < 4; ++kt)
#pragma unroll
                for (int T = 0; T < 8; ++T)
                    acc[T] = __builtin_amdgcn_mfma_f32_16x16x32_bf16(A[T][kt], B[kt].v, acc[T], 0, 0, 0);

            bool hit = (t == srow1);
            res  = hit ? acc[7][3] : res;
            resC = hit ? C : resC;

            const bool live = (t < srow1);
            float u[8][4];
#pragma unroll
            for (int T = 0; T < 8; ++T)
#pragma unroll
                for (int r = 0; r < 4; ++r) {
                    bool dead = !live || (T == 7 && l4 == 3 && r >= 2);
                    u[T][r] = dead ? 0.0f : acc[T][r] * __expf(pf.q[T][r]);
                }
            if (applyScale) {
#pragma unroll
                for (int T = 0; T < 8; ++T)
#pragma unroll
                    for (int r = 0; r < 4; ++r) u[T][r] *= 0x1p-64f;
                C += 44.3614195558365f;
            }
            applyScale = false;
            if (chk) {
                float m[8];
#pragma unroll
                for (int T = 0; T < 8; ++T)
                    m[T] = fmaxf(fmaxf(u[T][0], u[T][1]), fmaxf(u[T][2], u[T][3]));
                float mx4 = fmaxf(fmaxf(fmaxf(m[0], m[1]), fmaxf(m[2], m[3])),
                                  fmaxf(fmaxf(m[4], m[5]), fmaxf(m[6], m[7])));
                applyScale = (__ballot(mx4 > 0x1p80f) != 0ull);
            }
#pragma unroll
            for (int kt = 0; kt < 4; ++kt) {
                B[kt].i[0] = (int)pkbf(u[kt][0], u[kt][1]);
                B[kt].i[1] = (int)pkbf(u[kt][2], u[kt][3]);
                B[kt].i[2] = (int)pkbf(u[kt + 4][0], u[kt + 4][1]);
                B[kt].i[3] = (int)pkbf(u[kt + 4][2], u[kt + 4][3]);
            }
            loadPF(pf, min(t + 1, TDIM - 1));
        };
        for (int t0 = 0; t0 < tmaxR; t0 += 2) {
            stepF(t0 + 1, fa, true);
            stepF(t0 + 2, fb, false);
        }
    }

    if (l4 == 3)
        fwd_out[b] = __logf(res) + resC;
}

// ---------------------------------------------------------------------------
// Gold path score (unchanged, verified exact).
// ---------------------------------------------------------------------------
__global__ __launch_bounds__(256)
void crf_score(const float* __restrict__ pred,
               const float* __restrict__ trans,
               const int* __restrict__ tags,
               const int* __restrict__ seq_len,
               float* __restrict__ score_out)
{
    const int b = blockIdx.x;
    const int tid = threadIdx.x;
    const int sl = seq_len[b];
    const int* tg = tags + b * TDIM;

    float s = 0.0f;
    for (int t = tid; t < sl; t += 256) {
        int tag = tg[t];
        s += pred[((long)b * TDIM + t) * L + tag];
        int prev = (t == 0) ? START : tg[t - 1];
        s += trans[prev * L + tag];
    }
    if (tid == 0) s += trans[tg[sl - 1] * L + STOP];

    __shared__ float red[4];
#pragma unroll
    for (int d = 1; d < 64; d <<= 1) s += __shfl_xor(s, d);
    if ((tid & 63) == 0) red[tid >> 6] = s;
    __syncthreads();
    if (tid == 0) score_out[b] = (red[0] + red[1]) + (red[2] + red[3]);
}

__global__ __launch_bounds__(128)
void crf_combine(const float* __restrict__ fwd,
                 const float* __restrict__ real,
                 float* __restrict__ out)
{
    const int tid = threadIdx.x;
    float s = fwd[tid] - real[tid];
#pragma unroll
    for (int d = 1; d < 64; d <<= 1) s += __shfl_xor(s, d);
    __shared__ float red[2];
    if ((tid & 63) == 0) red[tid >> 6] = s;
    __syncthreads();
    if (tid == 0) out[0] = red[0] + red[1];
}

extern "C" void kernel_launch(void* const* d_in, const int* in_sizes, int n_in,
                              void* d_out, int out_size, void* d_ws, size_t ws_size,
                              hipStream_t stream)
{
    const float* pred    = (const float*)d_in[0];
    const float* trans   = (const float*)d_in[1];
    const int*   tags    = (const int*)d_in[2];
    const int*   seq_len = (const int*)d_in[3];

    float* ws   = (float*)d_ws;
    float* fwd  = ws;        // 128 floats
    float* real = ws + 128;  // 128 floats

    const size_t pexp_bytes = (size_t)NBLK * 1024 * 4096; // 33.5 MB
    if (ws_size >= 1024 + pexp_bytes) {
        unsigned short* pexp = (unsigned short*)((char*)d_ws + 1024);
        crf_pexp<<<8192, 256, 0, stream>>>(pred, seq_len, pexp);
        crf_chain<true><<<NBLK, 64, 0, stream>>>(pred, trans, seq_len, pexp, fwd);
    } else {
        crf_chain<false><<<NBLK, 64, 0, stream>>>(pred, trans, seq_len, nullptr, fwd);
    }
    crf_score  <<<NBATCH, 256, 0, stream>>>(pred, trans, tags, seq_len, real);
    crf_combine<<<1, 128, 0, stream>>>(fwd, real, (float*)d_out);
}